// Round 14
// baseline (31.139 us; speedup 1.0000x reference)
//
#include <hip/hip_runtime.h>
#include <math.h>

// SMEFTNet forward. B=128, N=128, H=16.  "Config Z": 2 nodes per wave,
// j-split across group pairs -> grid 2048 blocks (8 blocks/CU, targets
// 8 waves/SIMD if VGPR<=64). Epilogue-only loads deferred past the j-loop
// to minimize loop-live VGPRs.
// lane = g*16+t: node = g>>1 (2/wave), j-half = g&1, t = channel/j-sub.
// Reduce: 4-step DPP (16-lane) + xor16 swizzle (merge j-halves) +
// bpermute broadcast from lane (l|31). deg = 17th chain.
// conv0 epilogue: 2nd layer + gamma, rotation (ang1 = re,im,inv), proj
// u1/v1 in ONE full-wave pass (2 nodes x 32 outputs).
// conv1 epilogue: same + per-wave readout partials (mask odd groups,
// xor16 + xor32) -> part[8192][20]. K3: 1 wave/batch sums 64 rows + MLP.

#define BB 128
#define NN 128
#define BN (BB * NN)

typedef float f32x2 __attribute__((ext_vector_type(2)));

__device__ __forceinline__ f32x2 pk2(float s) { f32x2 r; r[0] = s; r[1] = s; return r; }
__device__ __forceinline__ f32x2 pkfma(f32x2 a, f32x2 b, f32x2 c) {
    return __builtin_elementwise_fma(a, b, c);
}
__device__ __forceinline__ f32x2 pkmax(f32x2 a, f32x2 b) {
    return __builtin_elementwise_max(a, b);
}

template <int CTRL>
__device__ __forceinline__ float dpp_add(float x) {
    int tmp = __builtin_amdgcn_update_dpp(0, __float_as_int(x), CTRL, 0xF, 0xF, true);
    return x + __int_as_float(tmp);
}

// Sum within each 16-lane row; result valid in lane (l|15) of each row.
__device__ __forceinline__ float grp16_sum(float x) {
    x = dpp_add<0xB1>(x);   // quad_perm [1,0,3,2]  (xor 1)
    x = dpp_add<0x4E>(x);   // quad_perm [2,3,0,1]  (xor 2)
    x = dpp_add<0x114>(x);  // row_shr:4
    x = dpp_add<0x118>(x);  // row_shr:8
    return x;
}

__device__ __forceinline__ float swz16_add(float x) {
    return x + __int_as_float(__builtin_amdgcn_ds_swizzle(__float_as_int(x), 0x401F));
}

__device__ __forceinline__ float bcast31(float x, int bidx) {
    return __int_as_float(__builtin_amdgcn_ds_bpermute(bidx, __float_as_int(x)));
}

// full per-node reduce: DPP-16 + xor16 merge + broadcast from lane (l|31)
__device__ __forceinline__ float node_sum(float x, int bidx) {
    return bcast31(swz16_add(grp16_sum(x)), bidx);
}

// ---------------- K1: conv0 + fused proj for conv1 ----------------
__global__ __launch_bounds__(256) void conv0_kernel(
    const float* __restrict__ ang,   // (B,N,2)
    const float* __restrict__ w0,    // c0_w0 (5,16)
    const float* __restrict__ b0,    // (16)
    const float* __restrict__ w1,    // c0_w1 (16,17)
    const float* __restrict__ b1,    // (17)
    const float* __restrict__ nw0,   // c1_w0 (50,16)
    const float* __restrict__ nb0,   // c1_b0 (16)
    float* __restrict__ ang1,        // (BN,4): re,im,inv,0
    float* __restrict__ u1,          // (BN,16)
    float* __restrict__ v1)          // (BN,16)
{
    const int tid  = threadIdx.x;
    const int lane = tid & 63;
    const int wid  = tid >> 6;
    const int t    = lane & 15;
    const int g    = lane >> 4;
    const int nloc = g >> 1;               // wave-local node 0/1
    const int jh   = g & 1;                // j-half
    const int ni   = blockIdx.x * 8 + wid * 2 + nloc;
    const int base = (blockIdx.x >> 4) << 7;   // batch start node

    __shared__ float hls[8][17];

    // my node
    const float2 ai = ((const float2*)ang)[ni];
    const float r2i = fmaf(ai.x, ai.x, ai.y * ai.y);
    const float abszi = __builtin_amdgcn_sqrtf(r2i);
    const float invi  = __builtin_amdgcn_rsqf(r2i);

    // layer-0 row constants (wave-uniform -> s_load) + per-lane u0b
    f32x2 u0b2[8], q02[8], wc2[8], ws2[8];
    #pragma unroll
    for (int p = 0; p < 8; ++p) {
        f32x2 wa  = *(const f32x2*)(w0 + 2 * p);
        f32x2 wb  = *(const f32x2*)(w0 + 16 + 2 * p);
        f32x2 wcv = *(const f32x2*)(w0 + 32 + 2 * p);
        f32x2 bb  = *(const f32x2*)(b0 + 2 * p);
        u0b2[p] = pkfma(pk2(abszi), wa - wcv, bb);   // absz_i*(Wa-Wc)+b0
        q02[p]  = wb + wcv;                          // Wb+Wc
        wc2[p]  = *(const f32x2*)(w0 + 48 + 2 * p);
        ws2[p]  = *(const f32x2*)(w0 + 64 + 2 * p);
    }

    // j-loop: 4 iters, j = jh*64 + jj*16 + t
    f32x2 A2[8];
    #pragma unroll
    for (int p = 0; p < 8; ++p) A2[p] = pk2(0.0f);
    float degf = 0.0f;

    #pragma unroll 4
    for (int jj = 0; jj < 4; ++jj) {
        const float2 aj = ((const float2*)ang)[base + jh * 64 + jj * 16 + t];
        const float r2j = fmaf(aj.x, aj.x, aj.y * aj.y);
        const float abszj = __builtin_amdgcn_sqrtf(r2j);
        const float ivj   = __builtin_amdgcn_rsqf(r2j);
        const float dre = ai.x - aj.x, dim = ai.y - aj.y;
        const float d2 = fmaf(dre, dre, dim * dim);
        const float adjf = (d2 <= 0.16f) ? 1.0f : 0.0f;
        degf += adjf;
        const float inv = fminf(invi * ivj, 1e12f);
        const f32x2 cos2 = pk2(fmaf(ai.x, aj.x, ai.y * aj.y) * inv);
        const f32x2 sin2 = pk2(fmaf(ai.y, aj.x, -(ai.x * aj.y)) * inv);
        const f32x2 ab2 = pk2(abszj);
        const f32x2 adj2 = pk2(adjf);
        #pragma unroll
        for (int p = 0; p < 8; ++p) {
            f32x2 z = pkfma(ab2, q02[p], u0b2[p]);
            z = pkfma(cos2, wc2[p], z);
            z = pkfma(sin2, ws2[p], z);
            f32x2 a = pkmax(z, z * 0.01f);
            A2[p] = pkfma(a, adj2, A2[p]);
        }
    }

    // reduce: 17 chains
    const int bidx = (lane | 31) << 2;
    float Ak[16];
    #pragma unroll
    for (int p = 0; p < 8; ++p) {
        Ak[2 * p]     = node_sum(A2[p][0], bidx);
        Ak[2 * p + 1] = node_sum(A2[p][1], bidx);
    }
    const float invdeg = __builtin_amdgcn_rcpf(node_sum(degf, bidx));

    // epilogue loads: w1 column t (per-lane) + gamma column (uniform)
    float s = 0.0f, sg = 0.0f;
    #pragma unroll
    for (int k = 0; k < 16; ++k) {
        s  = fmaf(Ak[k], w1[k * 17 + t], s);
        sg = fmaf(Ak[k], w1[k * 17 + 16], sg);
    }
    const float mt    = fmaf(s, invdeg, b1[t]);
    const float gamma = fmaf(sg, invdeg, b1[16]);

    // rotation (v_cos/v_sin take revolutions); norm preserved -> store invi
    {
        const float gf = gamma - floorf(gamma);
        const float cs = __builtin_amdgcn_cosf(gf);
        const float sn = __builtin_amdgcn_sinf(gf);
        const float re2 = cs * ai.x - sn * ai.y;
        const float im2 = fmaf(sn, ai.x, cs * ai.y);
        if (jh == 0 && t == 0) ((float4*)ang1)[ni] = make_float4(re2, im2, invi, 0.0f);
    }

    // h-exchange (same-wave LDS, no barrier needed; duplicate writes benign)
    hls[wid * 2 + nloc][t] = mt;

    // proj: ONE pass, 64 lanes = 2 nodes x (16 u + 16 v)
    const int pn  = lane >> 5;             // wave-local node for proj
    const int o   = lane & 31;
    const int kk  = o & 15;
    const bool isU = (o < 16);
    float acc = isU ? nb0[kk] : 0.0f;
    {
        const int off = isU ? 0 : 256;
        const float sgn = isU ? -1.0f : 1.0f;
        #pragma unroll
        for (int c = 0; c < 16; ++c) {
            const float a_ = nw0[off + c * 16 + kk];
            const float c_ = nw0[512 + c * 16 + kk];
            acc = fmaf(hls[wid * 2 + pn][c], fmaf(sgn, c_, a_), acc);
        }
    }
    const int nout = blockIdx.x * 8 + wid * 2 + pn;
    if (isU) u1[nout * 16 + kk] = acc;
    else     v1[nout * 16 + kk] = acc;
}

// ---------------- K2: conv1 + per-wave readout partials ----------------
__global__ __launch_bounds__(256) void conv1_kernel(
    const float* __restrict__ pt,    // (B,N)
    const float* __restrict__ ang1,  // (BN,4): re,im,inv,0
    const float* __restrict__ u1,    // (BN,16)
    const float* __restrict__ v1,    // (BN,16)
    const float* __restrict__ w0,    // c1_w0 (50,16)
    const float* __restrict__ w1,    // c1_w1 (16,17)
    const float* __restrict__ b1,    // (17)
    float* __restrict__ part)        // (8192,20)
{
    const int tid  = threadIdx.x;
    const int lane = tid & 63;
    const int wid  = tid >> 6;
    const int t    = lane & 15;
    const int g    = lane >> 4;
    const int nloc = g >> 1;
    const int jh   = g & 1;
    const int ni   = blockIdx.x * 8 + wid * 2 + nloc;
    const int base = (blockIdx.x >> 4) << 7;

    // my node
    const float4 a4 = ((const float4*)ang1)[ni];
    const float rei = a4.x, imi = a4.y, invi = a4.z;
    const float ptf = pt[ni];

    f32x2 u0b2[8], wc2[8], ws2[8];
    {
        const float4* ug = (const float4*)(u1 + (size_t)ni * 16);
        float4 q0 = ug[0], q1 = ug[1], q2 = ug[2], q3 = ug[3];
        u0b2[0][0] = q0.x; u0b2[0][1] = q0.y; u0b2[1][0] = q0.z; u0b2[1][1] = q0.w;
        u0b2[2][0] = q1.x; u0b2[2][1] = q1.y; u0b2[3][0] = q1.z; u0b2[3][1] = q1.w;
        u0b2[4][0] = q2.x; u0b2[4][1] = q2.y; u0b2[5][0] = q2.z; u0b2[5][1] = q2.w;
        u0b2[6][0] = q3.x; u0b2[6][1] = q3.y; u0b2[7][0] = q3.z; u0b2[7][1] = q3.w;
    }
    #pragma unroll
    for (int p = 0; p < 8; ++p) {
        wc2[p] = *(const f32x2*)(w0 + 768 + 2 * p);
        ws2[p] = *(const f32x2*)(w0 + 784 + 2 * p);
    }

    f32x2 A2[8];
    #pragma unroll
    for (int p = 0; p < 8; ++p) A2[p] = pk2(0.0f);
    float degf = 0.0f;

    #pragma unroll 2
    for (int jj = 0; jj < 4; ++jj) {
        const int j = base + jh * 64 + jj * 16 + t;
        const float4 aj = ((const float4*)ang1)[j];
        f32x2 vj2[8];
        {
            const float4* vg = (const float4*)(v1 + (size_t)j * 16);
            float4 q0 = vg[0], q1 = vg[1], q2 = vg[2], q3 = vg[3];
            vj2[0][0] = q0.x; vj2[0][1] = q0.y; vj2[1][0] = q0.z; vj2[1][1] = q0.w;
            vj2[2][0] = q1.x; vj2[2][1] = q1.y; vj2[3][0] = q1.z; vj2[3][1] = q1.w;
            vj2[4][0] = q2.x; vj2[4][1] = q2.y; vj2[5][0] = q2.z; vj2[5][1] = q2.w;
            vj2[6][0] = q3.x; vj2[6][1] = q3.y; vj2[7][0] = q3.z; vj2[7][1] = q3.w;
        }
        const float dre = rei - aj.x, dim = imi - aj.y;
        const float d2 = fmaf(dre, dre, dim * dim);
        const float adjf = (d2 <= 0.16f) ? 1.0f : 0.0f;
        degf += adjf;
        const float inv = fminf(invi * aj.z, 1e12f);
        const f32x2 cos2 = pk2(fmaf(rei, aj.x, imi * aj.y) * inv);
        const f32x2 sin2 = pk2(fmaf(imi, aj.x, -(rei * aj.y)) * inv);
        const f32x2 adj2 = pk2(adjf);
        #pragma unroll
        for (int p = 0; p < 8; ++p) {
            f32x2 z = u0b2[p] + vj2[p];
            z = pkfma(cos2, wc2[p], z);
            z = pkfma(sin2, ws2[p], z);
            f32x2 a = pkmax(z, z * 0.01f);
            A2[p] = pkfma(a, adj2, A2[p]);
        }
    }

    const int bidx = (lane | 31) << 2;
    float Ak[16];
    #pragma unroll
    for (int p = 0; p < 8; ++p) {
        Ak[2 * p]     = node_sum(A2[p][0], bidx);
        Ak[2 * p + 1] = node_sum(A2[p][1], bidx);
    }
    const float invdeg = __builtin_amdgcn_rcpf(node_sum(degf, bidx));

    // epilogue loads
    float s = 0.0f, sg = 0.0f;
    #pragma unroll
    for (int k = 0; k < 16; ++k) {
        s  = fmaf(Ak[k], w1[k * 17 + t], s);
        sg = fmaf(Ak[k], w1[k * 17 + 16], sg);
    }
    const float mt    = fmaf(s, invdeg, b1[t]);
    const float gamma = fmaf(sg, invdeg, b1[16]);

    const float gf = gamma - floorf(gamma);
    const float cs = __builtin_amdgcn_cosf(gf);
    const float sn = __builtin_amdgcn_sinf(gf);
    const float re2 = cs * rei - sn * imi;
    const float im2 = fmaf(sn, rei, cs * imi);

    // per-wave readout partials over 2 nodes: mask odd (duplicate) groups,
    // then xor16 (merge group pair) + xor32 (merge nodes).
    const float sel = (jh == 0) ? 1.0f : 0.0f;
    float pm  = sel * ptf * mt;
    float pre = sel * ptf * re2;
    float pim = sel * ptf * im2;
    float ppt = sel * ptf;
    pm  = swz16_add(pm);   pm  += __shfl_xor(pm, 32);
    pre = swz16_add(pre);  pre += __shfl_xor(pre, 32);
    pim = swz16_add(pim);  pim += __shfl_xor(pim, 32);
    ppt = swz16_add(ppt);  ppt += __shfl_xor(ppt, 32);

    float* po = part + (size_t)(blockIdx.x * 4 + wid) * 20;
    if (lane < 16)       po[lane] = pm;
    else if (lane == 16) po[16] = pre;
    else if (lane == 17) po[17] = pim;
    else if (lane == 18) po[18] = ppt;
}

// ---------------- K3: final readout (1 wave per batch) ----------------
__global__ __launch_bounds__(64) void readout_kernel(
    const float* __restrict__ part,  // (8192,20)
    const float* __restrict__ w0, const float* __restrict__ b0,  // (16,32),(32)
    const float* __restrict__ w1, const float* __restrict__ b1,  // (32,32),(32)
    const float* __restrict__ w2, const float* __restrict__ b2,  // (32,1),(1)
    float* __restrict__ out) {
    const int b = blockIdx.x;
    const int t = threadIdx.x;

    __shared__ float sbuf[19];
    __shared__ float xg[18];
    __shared__ float h1r[32];

    if (t < 19) {
        float s0 = 0.0f, s1 = 0.0f, s2 = 0.0f, s3 = 0.0f;
        const float* pb = part + (size_t)b * 64 * 20 + t;
        #pragma unroll
        for (int r = 0; r < 64; r += 4) {
            s0 += pb[(r + 0) * 20];
            s1 += pb[(r + 1) * 20];
            s2 += pb[(r + 2) * 20];
            s3 += pb[(r + 3) * 20];
        }
        sbuf[t] = (s0 + s1) + (s2 + s3);
    }
    // same wave: LDS ops are in-order, no barrier needed
    const float invd = __builtin_amdgcn_rcpf(sbuf[18]);
    if (t < 18) xg[t] = sbuf[t] * invd;

    if (t < 32) {
        float h = b0[t];
        #pragma unroll
        for (int k = 0; k < 16; ++k) h = fmaf(xg[k], w0[k * 32 + t], h);
        h = fmaxf(h, 0.01f * h);
        h1r[t] = h;
    }
    if (t < 32) {
        float h = b1[t];
        #pragma unroll
        for (int k = 0; k < 32; ++k) h = fmaf(h1r[k], w1[k * 32 + t], h);
        h = fmaxf(h, 0.01f * h);
        float p = h * w2[t];
        #pragma unroll
        for (int off = 16; off; off >>= 1) p += __shfl_xor(p, off);
        if (t == 0) {
            out[b * 3 + 0] = 1.0f / (1.0f + expf(-(p + b2[0])));
            out[b * 3 + 1] = xg[16];
            out[b * 3 + 2] = xg[17];
        }
    }
}

extern "C" void kernel_launch(void* const* d_in, const int* in_sizes, int n_in,
                              void* d_out, int out_size, void* d_ws, size_t ws_size,
                              hipStream_t stream) {
    const float* pt    = (const float*)d_in[0];
    const float* ang   = (const float*)d_in[1];
    const float* c0_w0 = (const float*)d_in[2];
    const float* c0_b0 = (const float*)d_in[3];
    const float* c0_w1 = (const float*)d_in[4];
    const float* c0_b1 = (const float*)d_in[5];
    const float* c1_w0 = (const float*)d_in[6];
    const float* c1_b0 = (const float*)d_in[7];
    const float* c1_w1 = (const float*)d_in[8];
    const float* c1_b1 = (const float*)d_in[9];
    const float* r_w0  = (const float*)d_in[10];
    const float* r_b0  = (const float*)d_in[11];
    const float* r_w1  = (const float*)d_in[12];
    const float* r_b1  = (const float*)d_in[13];
    const float* r_w2  = (const float*)d_in[14];
    const float* r_b2  = (const float*)d_in[15];
    float* out = (float*)d_out;
    float* ws = (float*)d_ws;

    float* ang1  = ws;                         // BN*4
    float* u1    = ang1 + (size_t)BN * 4;      // BN*16
    float* v1    = u1 + (size_t)BN * 16;       // BN*16
    float* partb = v1 + (size_t)BN * 16;       // 8192*20

    hipLaunchKernelGGL(conv0_kernel, dim3(BN / 8), dim3(256), 0, stream,
                       ang, c0_w0, c0_b0, c0_w1, c0_b1, c1_w0, c1_b0,
                       ang1, u1, v1);
    hipLaunchKernelGGL(conv1_kernel, dim3(BN / 8), dim3(256), 0, stream,
                       pt, ang1, u1, v1, c1_w0, c1_w1, c1_b1, partb);
    hipLaunchKernelGGL(readout_kernel, dim3(BB), dim3(64), 0, stream,
                       partb, r_w0, r_b0, r_w1, r_b1, r_w2, r_b2, out);
}